// Round 11
// baseline (95.887 us; speedup 1.0000x reference)
//
#include <hip/hip_runtime.h>

// out[i,j] = (z[i,:] . w) * w[j] + bias[j], all f32.  S=65536, B=1024.
// R11: fuse R9's two amortized bodies into one kernel (remove the inter-kernel
// drain + scal round-trip). 512 blocks x 512 threads, 2 rows/block:
//   phase 1: dot2 (each w load feeds 2 z-row FMAs), wave+LDS reduce
//   phase 2: write both rows, NT stores (each w/bias load pair feeds 4 stores)
// Blocks desynchronize (no global barrier) so the bus sees blended read/write
// traffic at the phase transition instead of a full-grid drain.

#define SDIM 65536
#define S4   16384     // float4 per row
#define BLK  512

typedef float floatx4 __attribute__((ext_vector_type(4)));

__device__ __forceinline__ float dot4(floatx4 a, floatx4 b) {
    return a.x * b.x + a.y * b.y + a.z * b.z + a.w * b.w;
}

__global__ __launch_bounds__(BLK) void fused2_kernel(
    const float* __restrict__ z,
    const float* __restrict__ w,
    const float* __restrict__ bias,
    float* __restrict__ out)
{
    const int r0 = blockIdx.x * 2;
    const floatx4* __restrict__ z0 =
        reinterpret_cast<const floatx4*>(z + (size_t)r0 * SDIM);
    const floatx4* __restrict__ z1 =
        reinterpret_cast<const floatx4*>(z + (size_t)(r0 + 1) * SDIM);
    const floatx4* __restrict__ w4 = reinterpret_cast<const floatx4*>(w);
    const floatx4* __restrict__ b4 = reinterpret_cast<const floatx4*>(bias);
    floatx4* __restrict__ o0 =
        reinterpret_cast<floatx4*>(out + (size_t)r0 * SDIM);
    floatx4* __restrict__ o1 =
        reinterpret_cast<floatx4*>(out + (size_t)(r0 + 1) * SDIM);

    // ---- phase 1: dot both rows (R9 dot2 body) ----
    float a00 = 0.f, a01 = 0.f, a02 = 0.f, a03 = 0.f;
    float a10 = 0.f, a11 = 0.f, a12 = 0.f, a13 = 0.f;
    for (int i = threadIdx.x; i < S4; i += 4 * BLK) {
        floatx4 y0 = w4[i];
        floatx4 y1 = w4[i + BLK];
        floatx4 y2 = w4[i + 2 * BLK];
        floatx4 y3 = w4[i + 3 * BLK];
        floatx4 p0 = z0[i];
        floatx4 p1 = z0[i + BLK];
        floatx4 p2 = z0[i + 2 * BLK];
        floatx4 p3 = z0[i + 3 * BLK];
        floatx4 q0 = z1[i];
        floatx4 q1 = z1[i + BLK];
        floatx4 q2 = z1[i + 2 * BLK];
        floatx4 q3 = z1[i + 3 * BLK];
        a00 += dot4(p0, y0); a01 += dot4(p1, y1);
        a02 += dot4(p2, y2); a03 += dot4(p3, y3);
        a10 += dot4(q0, y0); a11 += dot4(q1, y1);
        a12 += dot4(q2, y2); a13 += dot4(q3, y3);
    }
    float accA = (a00 + a01) + (a02 + a03);
    float accB = (a10 + a11) + (a12 + a13);

    #pragma unroll
    for (int off = 32; off > 0; off >>= 1) {
        accA += __shfl_down(accA, off, 64);
        accB += __shfl_down(accB, off, 64);
    }

    __shared__ float smem[BLK / 64][2];
    __shared__ float sb[2];
    const int lane = threadIdx.x & 63;
    const int wid  = threadIdx.x >> 6;
    if (lane == 0) { smem[wid][0] = accA; smem[wid][1] = accB; }
    __syncthreads();
    if (threadIdx.x < 2) {
        const int r = threadIdx.x;
        float t = 0.f;
        #pragma unroll
        for (int i = 0; i < BLK / 64; ++i) t += smem[i][r];
        sb[r] = t;
    }
    __syncthreads();
    const float s0 = sb[0];
    const float s1 = sb[1];

    // ---- phase 2: write both rows, NT stores, w/bias amortized 2x ----
    for (int i = threadIdx.x; i < S4; i += 2 * BLK) {
        floatx4 y0 = w4[i];
        floatx4 y1 = w4[i + BLK];
        floatx4 c0 = b4[i];
        floatx4 c1 = b4[i + BLK];
        floatx4 t;
        t.x = fmaf(s0, y0.x, c0.x); t.y = fmaf(s0, y0.y, c0.y);
        t.z = fmaf(s0, y0.z, c0.z); t.w = fmaf(s0, y0.w, c0.w);
        __builtin_nontemporal_store(t, &o0[i]);
        t.x = fmaf(s1, y0.x, c0.x); t.y = fmaf(s1, y0.y, c0.y);
        t.z = fmaf(s1, y0.z, c0.z); t.w = fmaf(s1, y0.w, c0.w);
        __builtin_nontemporal_store(t, &o1[i]);
        t.x = fmaf(s0, y1.x, c1.x); t.y = fmaf(s0, y1.y, c1.y);
        t.z = fmaf(s0, y1.z, c1.z); t.w = fmaf(s0, y1.w, c1.w);
        __builtin_nontemporal_store(t, &o0[i + BLK]);
        t.x = fmaf(s1, y1.x, c1.x); t.y = fmaf(s1, y1.y, c1.y);
        t.z = fmaf(s1, y1.z, c1.z); t.w = fmaf(s1, y1.w, c1.w);
        __builtin_nontemporal_store(t, &o1[i + BLK]);
    }
}

extern "C" void kernel_launch(void* const* d_in, const int* in_sizes, int n_in,
                              void* d_out, int out_size, void* d_ws, size_t ws_size,
                              hipStream_t stream)
{
    const float* z    = (const float*)d_in[0];
    const float* w    = (const float*)d_in[1];  // (1,S,1) flat == (S,)
    const float* bias = (const float*)d_in[2];
    float* out = (float*)d_out;

    const int B = in_sizes[0] / SDIM;           // 1024

    fused2_kernel<<<B / 2, BLK, 0, stream>>>(z, w, bias, out);
}

// Round 12
// 95.229 us; speedup vs baseline: 1.0069x; 1.0069x over previous
//
#include <hip/hip_runtime.h>

// out[i,j] = (z[i,:] . w) * w[j] + bias[j], all f32.  S=65536, B=1024.
// R12 = R9 split (best: 93.9us) with final micro-tuning:
//  - dot2: unroll 8 (16 z-loads + 4 w-loads in flight), XCD-aware block
//    swizzle (8 XCDs; consecutive-on-XCD blocks read contiguous z).
//  - outer4: finer blocks (2048 blocks x 256 thr) to shrink tail skew.
// NT stores; plain z loads (NT loads regressed, R8).

#define SDIM 65536
#define S4   16384     // float4 per row
#define BLK  512
#define NXCD 8

typedef float floatx4 __attribute__((ext_vector_type(4)));

__device__ __forceinline__ float dot4(floatx4 a, floatx4 b) {
    return a.x * b.x + a.y * b.y + a.z * b.z + a.w * b.w;
}

// ---------------- kernel A: scal[r] = z[r,:] . w, 2 rows per block ----------
__global__ __launch_bounds__(BLK) void dot2_kernel(
    const float* __restrict__ z,
    const float* __restrict__ w,
    float* __restrict__ scal)
{
    // XCD-aware swizzle (gridDim.x = 512, divisible by 8): blocks resident on
    // one XCD get a contiguous chunk of rows.
    const int nwg  = gridDim.x;
    const int cpx  = nwg / NXCD;
    const int bid  = blockIdx.x;
    const int swz  = (bid % NXCD) * cpx + bid / NXCD;
    const int r0   = swz * 2;

    const floatx4* __restrict__ z0 =
        reinterpret_cast<const floatx4*>(z + (size_t)r0 * SDIM);
    const floatx4* __restrict__ z1 =
        reinterpret_cast<const floatx4*>(z + (size_t)(r0 + 1) * SDIM);
    const floatx4* __restrict__ w4 = reinterpret_cast<const floatx4*>(w);

    // unroll 8: per iter 4 w loads + 16 z loads in flight, 8 accum chains.
    // 16384 f4 / 512 thr = 32 per thread -> 4 outer iterations... (8*BLK=4096
    // stride, 4 iters)
    float a00 = 0.f, a01 = 0.f, a02 = 0.f, a03 = 0.f;
    float a10 = 0.f, a11 = 0.f, a12 = 0.f, a13 = 0.f;
    for (int i = threadIdx.x; i < S4; i += 8 * BLK) {
        floatx4 y0 = w4[i];
        floatx4 y1 = w4[i + BLK];
        floatx4 y2 = w4[i + 2 * BLK];
        floatx4 y3 = w4[i + 3 * BLK];
        floatx4 y4 = w4[i + 4 * BLK];
        floatx4 y5 = w4[i + 5 * BLK];
        floatx4 y6 = w4[i + 6 * BLK];
        floatx4 y7 = w4[i + 7 * BLK];
        floatx4 p0 = z0[i];
        floatx4 p1 = z0[i + BLK];
        floatx4 p2 = z0[i + 2 * BLK];
        floatx4 p3 = z0[i + 3 * BLK];
        floatx4 p4 = z0[i + 4 * BLK];
        floatx4 p5 = z0[i + 5 * BLK];
        floatx4 p6 = z0[i + 6 * BLK];
        floatx4 p7 = z0[i + 7 * BLK];
        floatx4 q0 = z1[i];
        floatx4 q1 = z1[i + BLK];
        floatx4 q2 = z1[i + 2 * BLK];
        floatx4 q3 = z1[i + 3 * BLK];
        floatx4 q4 = z1[i + 4 * BLK];
        floatx4 q5 = z1[i + 5 * BLK];
        floatx4 q6 = z1[i + 6 * BLK];
        floatx4 q7 = z1[i + 7 * BLK];
        a00 += dot4(p0, y0); a01 += dot4(p1, y1);
        a02 += dot4(p2, y2); a03 += dot4(p3, y3);
        a00 += dot4(p4, y4); a01 += dot4(p5, y5);
        a02 += dot4(p6, y6); a03 += dot4(p7, y7);
        a10 += dot4(q0, y0); a11 += dot4(q1, y1);
        a12 += dot4(q2, y2); a13 += dot4(q3, y3);
        a10 += dot4(q4, y4); a11 += dot4(q5, y5);
        a12 += dot4(q6, y6); a13 += dot4(q7, y7);
    }
    float accA = (a00 + a01) + (a02 + a03);
    float accB = (a10 + a11) + (a12 + a13);

    #pragma unroll
    for (int off = 32; off > 0; off >>= 1) {
        accA += __shfl_down(accA, off, 64);
        accB += __shfl_down(accB, off, 64);
    }

    __shared__ float smem[BLK / 64][2];
    const int lane = threadIdx.x & 63;
    const int wid  = threadIdx.x >> 6;
    if (lane == 0) { smem[wid][0] = accA; smem[wid][1] = accB; }
    __syncthreads();
    if (threadIdx.x < 2) {
        const int r = threadIdx.x;
        float t = 0.f;
        #pragma unroll
        for (int i = 0; i < BLK / 64; ++i) t += smem[i][r];
        scal[r0 + r] = t;
    }
}

// ------------- kernel B: out[r,:] = scal[r]*w + bias, 4 rows per block ------
#define OBLK   256
#define ORROWS 4
#define NCHUNK 8
#define CHUNK4 (S4 / NCHUNK)   // 2048 float4

__global__ __launch_bounds__(OBLK) void outer4_kernel(
    const float* __restrict__ scal,
    const float* __restrict__ w,
    const float* __restrict__ bias,
    float* __restrict__ out)
{
    const int group = blockIdx.x >> 3;        // row group of 4
    const int chunk = blockIdx.x & (NCHUNK - 1);
    const int r0    = group * ORROWS;
    const int base  = chunk * CHUNK4;

    const float s0 = scal[r0];
    const float s1 = scal[r0 + 1];
    const float s2 = scal[r0 + 2];
    const float s3 = scal[r0 + 3];

    const floatx4* __restrict__ w4 = reinterpret_cast<const floatx4*>(w) + base;
    const floatx4* __restrict__ b4 = reinterpret_cast<const floatx4*>(bias) + base;
    floatx4* __restrict__ o0 =
        reinterpret_cast<floatx4*>(out + (size_t)r0 * SDIM) + base;
    floatx4* __restrict__ o1 =
        reinterpret_cast<floatx4*>(out + (size_t)(r0 + 1) * SDIM) + base;
    floatx4* __restrict__ o2 =
        reinterpret_cast<floatx4*>(out + (size_t)(r0 + 2) * SDIM) + base;
    floatx4* __restrict__ o3 =
        reinterpret_cast<floatx4*>(out + (size_t)(r0 + 3) * SDIM) + base;

    // 2048 f4 / 256 thr = 8 iters; unroll 2 -> per iter 4 loads, 8 NT stores
    for (int i = threadIdx.x; i < CHUNK4; i += 2 * OBLK) {
        floatx4 y0 = w4[i];
        floatx4 y1 = w4[i + OBLK];
        floatx4 c0 = b4[i];
        floatx4 c1 = b4[i + OBLK];

        floatx4 t;
        t.x = fmaf(s0, y0.x, c0.x); t.y = fmaf(s0, y0.y, c0.y);
        t.z = fmaf(s0, y0.z, c0.z); t.w = fmaf(s0, y0.w, c0.w);
        __builtin_nontemporal_store(t, &o0[i]);
        t.x = fmaf(s1, y0.x, c0.x); t.y = fmaf(s1, y0.y, c0.y);
        t.z = fmaf(s1, y0.z, c0.z); t.w = fmaf(s1, y0.w, c0.w);
        __builtin_nontemporal_store(t, &o1[i]);
        t.x = fmaf(s2, y0.x, c0.x); t.y = fmaf(s2, y0.y, c0.y);
        t.z = fmaf(s2, y0.z, c0.z); t.w = fmaf(s2, y0.w, c0.w);
        __builtin_nontemporal_store(t, &o2[i]);
        t.x = fmaf(s3, y0.x, c0.x); t.y = fmaf(s3, y0.y, c0.y);
        t.z = fmaf(s3, y0.z, c0.z); t.w = fmaf(s3, y0.w, c0.w);
        __builtin_nontemporal_store(t, &o3[i]);

        t.x = fmaf(s0, y1.x, c1.x); t.y = fmaf(s0, y1.y, c1.y);
        t.z = fmaf(s0, y1.z, c1.z); t.w = fmaf(s0, y1.w, c1.w);
        __builtin_nontemporal_store(t, &o0[i + OBLK]);
        t.x = fmaf(s1, y1.x, c1.x); t.y = fmaf(s1, y1.y, c1.y);
        t.z = fmaf(s1, y1.z, c1.z); t.w = fmaf(s1, y1.w, c1.w);
        __builtin_nontemporal_store(t, &o1[i + OBLK]);
        t.x = fmaf(s2, y1.x, c1.x); t.y = fmaf(s2, y1.y, c1.y);
        t.z = fmaf(s2, y1.z, c1.z); t.w = fmaf(s2, y1.w, c1.w);
        __builtin_nontemporal_store(t, &o2[i + OBLK]);
        t.x = fmaf(s3, y1.x, c1.x); t.y = fmaf(s3, y1.y, c1.y);
        t.z = fmaf(s3, y1.z, c1.z); t.w = fmaf(s3, y1.w, c1.w);
        __builtin_nontemporal_store(t, &o3[i + OBLK]);
    }
}

extern "C" void kernel_launch(void* const* d_in, const int* in_sizes, int n_in,
                              void* d_out, int out_size, void* d_ws, size_t ws_size,
                              hipStream_t stream)
{
    const float* z    = (const float*)d_in[0];
    const float* w    = (const float*)d_in[1];  // (1,S,1) flat == (S,)
    const float* bias = (const float*)d_in[2];
    float* out  = (float*)d_out;
    float* scal = (float*)d_ws;                 // B floats of scratch

    const int B = in_sizes[0] / SDIM;           // 1024

    dot2_kernel<<<B / 2, BLK, 0, stream>>>(z, w, scal);
    outer4_kernel<<<(B / ORROWS) * NCHUNK, OBLK, 0, stream>>>(scal, w, bias, out);
}